// Round 1
// baseline (171.113 us; speedup 1.0000x reference)
//
#include <hip/hip_runtime.h>
#include <math.h>

// SSIM on (16,3,512,512) fp32, 11x11 Gaussian window (sigma=1.5), VALID conv,
// output = per-batch mean of SSIM map -> float[16].
//
// Separable conv: window = outer(g,g). 5 channels: r, d, r*r, d*d, r*d.
// One block per 32(H)x64(W) output tile of one (b,c) image.

#define WSZ 11
#define TW 64                 // output tile width
#define TH 32                 // output tile height
#define IW (TW + WSZ - 1)     // 74 input cols staged
#define IH (TH + WSZ - 1)     // 42 input rows staged
#define NT 256
#define IMG 512
#define OH 502
#define OW 502

struct WinArg { float w[WSZ]; };

__global__ __launch_bounds__(NT) void ssim_main(
    const float* __restrict__ raw, const float* __restrict__ dst,
    float* __restrict__ out, WinArg wa, float inv_n)
{
    __shared__ float sraw[IH][IW];
    __shared__ float sdst[IH][IW];
    __shared__ float hbuf[5][IH][TW];   // horizontal partial sums

    const int tid = threadIdx.x;
    const int bc  = blockIdx.z;         // b*3 + c
    const int bb  = bc / 3;
    const int r0  = blockIdx.y * TH;    // output-row base == input-row base
    const int c0  = blockIdx.x * TW;
    const size_t base = (size_t)bc * (size_t)(IMG * IMG);

    // ---- stage input tile (x255 folded in), zero-fill out-of-range ----
    for (int idx = tid; idx < IH * IW; idx += NT) {
        const int r  = idx / IW;
        const int cc = idx - r * IW;
        const int gr = r0 + r, gc = c0 + cc;
        float vr = 0.f, vd = 0.f;
        if (gr < IMG && gc < IMG) {
            const size_t off = base + (size_t)gr * IMG + gc;
            vr = raw[off] * 255.0f;
            vd = dst[off] * 255.0f;
        }
        sraw[r][cc] = vr;
        sdst[r][cc] = vd;
    }
    __syncthreads();

    // ---- horizontal pass: 5 windowed sums along W ----
    for (int p = tid; p < IH * TW; p += NT) {
        const int r = p >> 6;           // TW == 64
        const int j = p & (TW - 1);
        float s1 = 0.f, s2 = 0.f, s3 = 0.f, s4 = 0.f, s5 = 0.f;
#pragma unroll
        for (int k = 0; k < WSZ; k++) {
            const float wv = wa.w[k];
            const float R = sraw[r][j + k];
            const float D = sdst[r][j + k];
            s1 = fmaf(wv, R, s1);
            s2 = fmaf(wv, D, s2);
            s3 = fmaf(wv * R, R, s3);
            s4 = fmaf(wv * D, D, s4);
            s5 = fmaf(wv * R, D, s5);
        }
        hbuf[0][r][j] = s1;
        hbuf[1][r][j] = s2;
        hbuf[2][r][j] = s3;
        hbuf[3][r][j] = s4;
        hbuf[4][r][j] = s5;
    }
    __syncthreads();

    // ---- vertical pass + SSIM ----
    const int vh = min(TH, OH - r0);
    const int vw = min(TW, OW - c0);
    float acc = 0.f;
    for (int p = tid; p < TH * TW; p += NT) {
        const int oy = p >> 6;
        const int ox = p & (TW - 1);
        if (oy < vh && ox < vw) {
            float m1 = 0.f, m2 = 0.f, m3 = 0.f, m4 = 0.f, m5 = 0.f;
#pragma unroll
            for (int k = 0; k < WSZ; k++) {
                const float wv = wa.w[k];
                m1 = fmaf(wv, hbuf[0][oy + k][ox], m1);
                m2 = fmaf(wv, hbuf[1][oy + k][ox], m2);
                m3 = fmaf(wv, hbuf[2][oy + k][ox], m3);
                m4 = fmaf(wv, hbuf[3][oy + k][ox], m4);
                m5 = fmaf(wv, hbuf[4][oy + k][ox], m5);
            }
            const float C1 = 6.5025f;    // (0.01*255)^2
            const float C2 = 58.5225f;   // (0.03*255)^2
            const float musq1 = m1 * m1;
            const float musq2 = m2 * m2;
            const float mumu  = m1 * m2;
            const float numer = (2.0f * mumu + C1) * (2.0f * (m5 - mumu) + C2);
            const float denom = (musq1 + musq2 + C1) * ((m3 - musq1) + (m4 - musq2) + C2);
            acc += numer / denom;
        }
    }

    // ---- block reduction -> one atomicAdd per block ----
#pragma unroll
    for (int o = 32; o > 0; o >>= 1) acc += __shfl_down(acc, o, 64);
    __shared__ float wsum[NT / 64];
    if ((tid & 63) == 0) wsum[tid >> 6] = acc;
    __syncthreads();
    if (tid == 0) {
        float tot = wsum[0] + wsum[1] + wsum[2] + wsum[3];
        atomicAdd(out + bb, tot * inv_n);
    }
}

extern "C" void kernel_launch(void* const* d_in, const int* in_sizes, int n_in,
                              void* d_out, int out_size, void* d_ws, size_t ws_size,
                              hipStream_t stream) {
    const float* raw = (const float*)d_in[0];
    const float* dst = (const float*)d_in[1];
    float* out = (float*)d_out;

    // zero the accumulation target every call (graph-capture safe)
    hipMemsetAsync(out, 0, (size_t)out_size * sizeof(float), stream);

    // Gaussian window weights computed in double on host (matches numpy float64)
    WinArg wa;
    double g[WSZ], s = 0.0;
    for (int i = 0; i < WSZ; i++) {
        double ax = (double)i - (double)(WSZ - 1) / 2.0;
        g[i] = exp(-(ax * ax) / (2.0 * 1.5 * 1.5));
        s += g[i];
    }
    for (int i = 0; i < WSZ; i++) wa.w[i] = (float)(g[i] / s);

    const float inv_n = (float)(1.0 / (3.0 * (double)OH * (double)OW));

    dim3 grid((OW + TW - 1) / TW, (OH + TH - 1) / TH, 48);
    ssim_main<<<grid, NT, 0, stream>>>(raw, dst, out, wa, inv_n);
}

// Round 2
// 90.094 us; speedup vs baseline: 1.8993x; 1.8993x over previous
//
#include <hip/hip_runtime.h>
#include <math.h>

// SSIM (16,3,512,512) fp32, 11x11 separable Gaussian, VALID -> per-batch mean [16].
//
// Column-streaming design: each thread owns 2 adjacent output columns and keeps
// an 11-row ring of horizontal sums (5 ch x 2 cols) entirely in registers.
// Input rows are staged full-width into LDS via global_load_lds (width 16).
// The 255x scaling cancels algebraically: use C1 = 1e-4, C2 = 9e-4 on [0,1] data.

#define WSZ 11
#define IMG 512
#define OSZ 502          // IMG - WSZ + 1
#define NT  256
#define CH_OUT 32        // output rows per block
#define NCHUNK 16        // ceil(502/32)
#define NGROUP 4         // ceil((CH_OUT + WSZ - 1)/WSZ)

struct WinArg { float w[WSZ]; };

typedef const __attribute__((address_space(1))) unsigned int* gp_t;
typedef __attribute__((address_space(3))) unsigned int* sp_t;

__device__ __forceinline__ float ssim_val(float mu1, float mu2, float e11, float e22, float e12) {
    const float C1 = 1.0e-4f;   // (0.01*255)^2 / 255^2
    const float C2 = 9.0e-4f;   // (0.03*255)^2 / 255^2
    const float mumu = mu1 * mu2;
    const float q1 = mu1 * mu1, q2 = mu2 * mu2;
    const float cov = e12 - mumu, v1 = e11 - q1, v2 = e22 - q2;
    const float num = (2.0f * mumu + C1) * (2.0f * cov + C2);
    const float den = (q1 + q2 + C1) * (v1 + v2 + C2);
    return num / den;
}

__global__ __launch_bounds__(NT, 2) void ssim_col(
    const float* __restrict__ rawp, const float* __restrict__ dstp,
    float* __restrict__ out, WinArg wa, float inv_n)
{
    __shared__ float srow[2][WSZ][IMG];   // [channel][ring slot][col] = 45056 B
    __shared__ float wred[NT / 64];

    const int tid  = threadIdx.x;
    const int lane = tid & 63;
    const int wave = tid >> 6;
    const int chunk = blockIdx.x;
    const int img   = blockIdx.y;
    const int o0   = chunk * CH_OUT;             // first output row of this block
    const int olim = min(o0 + CH_OUT, OSZ);
    const size_t base = (size_t)img * (size_t)(IMG * IMG);
    const int x = tid * 2;                       // 2 output columns per thread
    const bool tval = (x + 1) < OSZ;

    float w[WSZ];
#pragma unroll
    for (int j = 0; j < WSZ; ++j) w[j] = wa.w[j];

    float hs[WSZ][5][2];                         // register ring: [slot][chan][col]
    float acc = 0.0f;

    const int rlast = min(o0 + CH_OUT + WSZ - 2, IMG - 1);  // last input row needed

#pragma unroll 1
    for (int g = 0; g < NGROUP; ++g) {
        const int rbase = o0 + g * WSZ;
        if (rbase > rlast) break;                // uniform per block

        // ---- stage up to 11 rows x 2 channels (44 half-row loads over 4 waves) ----
#pragma unroll
        for (int i = 0; i < WSZ; ++i) {
            const int q = wave * WSZ + i;        // 0..43, wave-uniform
            const int k = q >> 2;
            const int ch = (q >> 1) & 1;
            const int half = q & 1;
            const int gr = rbase + k;
            if (gr <= rlast) {
                const float* src = (ch ? dstp : rawp) + base + (size_t)gr * IMG
                                 + half * 256 + lane * 4;            // 16B per lane
                float* lp = &srow[ch][k][half * 256];
                __builtin_amdgcn_global_load_lds((gp_t)(const void*)src,
                                                 (sp_t)(void*)lp, 16, 0, 0);
            }
        }
        __syncthreads();   // compiler drains vmcnt before barrier -> data ready

        // ---- consume 11 rows: horizontal sums -> register ring -> vertical+SSIM ----
#pragma unroll
        for (int k = 0; k < WSZ; ++k) {
            if (tval) {
                const float2* rp = (const float2*)&srow[0][k][x];
                const float2* dp = (const float2*)&srow[1][k][x];
                float R[12], D[12];
#pragma unroll
                for (int j = 0; j < 6; ++j) {
                    const float2 rv = rp[j], dv = dp[j];
                    R[2 * j] = rv.x; R[2 * j + 1] = rv.y;
                    D[2 * j] = dv.x; D[2 * j + 1] = dv.y;
                }
                float s0a = 0.f, s1a = 0.f, s2a = 0.f, s3a = 0.f, s4a = 0.f;
                float s0b = 0.f, s1b = 0.f, s2b = 0.f, s3b = 0.f, s4b = 0.f;
#pragma unroll
                for (int j = 0; j < WSZ; ++j) {
                    const float wj = w[j];
                    {
                        const float r = R[j], d = D[j];
                        const float wr = wj * r, wd = wj * d;
                        s0a = fmaf(wj, r, s0a);
                        s1a = fmaf(wj, d, s1a);
                        s2a = fmaf(wr, r, s2a);
                        s3a = fmaf(wd, d, s3a);
                        s4a = fmaf(wr, d, s4a);
                    }
                    {
                        const float r = R[j + 1], d = D[j + 1];
                        const float wr = wj * r, wd = wj * d;
                        s0b = fmaf(wj, r, s0b);
                        s1b = fmaf(wj, d, s1b);
                        s2b = fmaf(wr, r, s2b);
                        s3b = fmaf(wd, d, s3b);
                        s4b = fmaf(wr, d, s4b);
                    }
                }
                hs[k][0][0] = s0a; hs[k][1][0] = s1a; hs[k][2][0] = s2a;
                hs[k][3][0] = s3a; hs[k][4][0] = s4a;
                hs[k][0][1] = s0b; hs[k][1][1] = s1b; hs[k][2][1] = s2b;
                hs[k][3][1] = s3b; hs[k][4][1] = s4b;
            }

            const int klin = g * WSZ + k;            // row index within chunk
            const int o = o0 + klin - (WSZ - 1);     // output row fed by this row
            if (klin >= WSZ - 1 && o < olim && tval) {
                float m0a = 0.f, m1a = 0.f, m2a = 0.f, m3a = 0.f, m4a = 0.f;
                float m0b = 0.f, m1b = 0.f, m2b = 0.f, m3b = 0.f, m4b = 0.f;
#pragma unroll
                for (int m = 0; m < WSZ; ++m) {
                    const int s = (k + 1 + m) % WSZ;  // compile-time after unroll
                    const float wm = w[m];
                    m0a = fmaf(wm, hs[s][0][0], m0a);
                    m1a = fmaf(wm, hs[s][1][0], m1a);
                    m2a = fmaf(wm, hs[s][2][0], m2a);
                    m3a = fmaf(wm, hs[s][3][0], m3a);
                    m4a = fmaf(wm, hs[s][4][0], m4a);
                    m0b = fmaf(wm, hs[s][0][1], m0b);
                    m1b = fmaf(wm, hs[s][1][1], m1b);
                    m2b = fmaf(wm, hs[s][2][1], m2b);
                    m3b = fmaf(wm, hs[s][3][1], m3b);
                    m4b = fmaf(wm, hs[s][4][1], m4b);
                }
                acc += ssim_val(m0a, m1a, m2a, m3a, m4a);
                acc += ssim_val(m0b, m1b, m2b, m3b, m4b);
            }
        }
        __syncthreads();   // all waves done reading before next group's staging
    }

    // ---- block reduction -> one atomicAdd per block ----
#pragma unroll
    for (int off = 32; off > 0; off >>= 1) acc += __shfl_down(acc, off, 64);
    if (lane == 0) wred[wave] = acc;
    __syncthreads();
    if (tid == 0) {
        const float tot = (wred[0] + wred[1]) + (wred[2] + wred[3]);
        atomicAdd(out + img / 3, tot * inv_n);
    }
}

extern "C" void kernel_launch(void* const* d_in, const int* in_sizes, int n_in,
                              void* d_out, int out_size, void* d_ws, size_t ws_size,
                              hipStream_t stream) {
    const float* raw = (const float*)d_in[0];
    const float* dst = (const float*)d_in[1];
    float* out = (float*)d_out;

    hipMemsetAsync(out, 0, (size_t)out_size * sizeof(float), stream);

    WinArg wa;
    double g[WSZ], s = 0.0;
    for (int i = 0; i < WSZ; ++i) {
        double ax = (double)i - (double)(WSZ - 1) / 2.0;
        g[i] = exp(-(ax * ax) / (2.0 * 1.5 * 1.5));
        s += g[i];
    }
    for (int i = 0; i < WSZ; ++i) wa.w[i] = (float)(g[i] / s);

    const float inv_n = (float)(1.0 / (3.0 * (double)OSZ * (double)OSZ));

    dim3 grid(NCHUNK, 48);
    ssim_col<<<grid, NT, 0, stream>>>(raw, dst, out, wa, inv_n);
}